// Round 1
// baseline (7636.322 us; speedup 1.0000x reference)
//
#include <hip/hip_runtime.h>

#define DD_ 16
#define HW 3136
#define DHW 50176
#define NEL 25690112   // 8*64*16*56*56
#define CNT 401408.0f  // 8*16*56*56

// ---------------- standard 3x3x3 conv, stride 1, pad 1, NCO output channels ----
template<int NCO>
__global__ __launch_bounds__(256) void k_conv3(
    const float* __restrict__ src, const float* __restrict__ w,
    const float* __restrict__ bias, float* __restrict__ dst)
{
    __shared__ float tile[1044]; // 3 d x 6 h x 58 w halo tile
    const int bz = blockIdx.y;
    const int n = bz >> 4, dd = bz & 15;
    const int h_base = blockIdx.x * 4;
    const int tid = threadIdx.x;
    const int ty = tid >> 6, tx = tid & 63;
    float acc[NCO];
#pragma unroll
    for (int i = 0; i < NCO; ++i) acc[i] = 0.f;
    const float* sn = src + (size_t)n * 64 * DHW;
    for (int ci = 0; ci < 64; ++ci) {
        __syncthreads();
        const float* sc = sn + (size_t)ci * DHW;
        for (int l = tid; l < 1044; l += 256) {
            int kd = l / 348; int r = l - kd * 348;
            int hh = r / 58;  int ww = r - hh * 58;
            int d = dd + kd - 1, h = h_base + hh - 1, wq = ww - 1;
            float v = 0.f;
            if ((unsigned)d < 16u && (unsigned)h < 56u && (unsigned)wq < 56u)
                v = sc[d * HW + h * 56 + wq];
            tile[l] = v;
        }
        __syncthreads();
        if (tx < 56) {
            float val[27];
#pragma unroll
            for (int kd = 0; kd < 3; ++kd)
#pragma unroll
                for (int kh = 0; kh < 3; ++kh)
#pragma unroll
                    for (int kw = 0; kw < 3; ++kw)
                        val[kd * 9 + kh * 3 + kw] =
                            tile[kd * 348 + (ty + kh) * 58 + (tx + kw)];
            const float* wp = w + ci * 27;   // block-uniform -> s_load path
#pragma unroll
            for (int co = 0; co < NCO; ++co) {
                float s = acc[co];
#pragma unroll
                for (int t = 0; t < 27; ++t)
                    s = fmaf(val[t], wp[co * 1728 + t], s);
                acc[co] = s;
            }
        }
    }
    if (tx < 56) {
        const size_t sp = (size_t)dd * HW + (size_t)(h_base + ty) * 56 + tx;
#pragma unroll
        for (int co = 0; co < NCO; ++co)
            dst[(size_t)(n * NCO + co) * (DD_ * HW) + sp] = acc[co] + bias[co];
    }
}

// ---------------- temporal deformable conv (ConvOffset3d), no bias ------------
__global__ __launch_bounds__(256) void k_deform(
    const float* __restrict__ x, const float* __restrict__ off,
    const float* __restrict__ w, float* __restrict__ dst)
{
    __shared__ int   i0s[8 * 348];
    __shared__ float fss[8 * 348];
    const int bz = blockIdx.y;
    const int n = bz >> 4, dd = bz & 15;
    const int h_base = blockIdx.x * 4;
    const int tid = threadIdx.x;
    const int ty = tid >> 6, tx = tid & 63;
    // stage per-group interpolation state for the 6x58 halo tile
    for (int l = tid; l < 8 * 348; l += 256) {
        int g = l / 348; int r = l - g * 348;
        int hh = r / 58; int ww = r - hh * 58;
        int h = h_base + hh - 1, wq = ww - 1;
        float p = 0.f;
        if ((unsigned)h < 56u && (unsigned)wq < 56u)
            p = off[(size_t)(n * 8 + g) * (DD_ * HW) + (size_t)dd * HW + h * 56 + wq]
                + (float)dd;
        float fl = floorf(p);
        i0s[l] = (int)fl;
        fss[l] = p - fl;
    }
    float acc[64];
#pragma unroll
    for (int i = 0; i < 64; ++i) acc[i] = 0.f;
    __syncthreads();
    const float* xn = x + (size_t)n * 64 * DHW;
    for (int ci = 0; ci < 64; ++ci) {
        const int g = ci >> 3;
        const float* xc = xn + (size_t)ci * DHW;
        if (tx < 56) {
            float Gv[27];
#pragma unroll
            for (int kh = 0; kh < 3; ++kh)
#pragma unroll
                for (int kw = 0; kw < 3; ++kw) {
                    const int hh = ty + kh, ww = tx + kw;
                    const int l = g * 348 + hh * 58 + ww;
                    const int h = h_base + hh - 1, wq = tx + kw - 1;
                    const bool sval = ((unsigned)h < 56u) & ((unsigned)wq < 56u);
                    const int i0 = i0s[l];
                    const float f = fss[l];
                    const int sp = h * 56 + wq;
                    float xv[4];
#pragma unroll
                    for (int j = 0; j < 4; ++j) {
                        const int dj = i0 - 1 + j;   // D sample indices i0-1..i0+2
                        xv[j] = (sval && (unsigned)dj < 16u)
                                    ? xc[dj * HW + sp] : 0.f;
                    }
#pragma unroll
                    for (int kd = 0; kd < 3; ++kd)
                        Gv[kd * 9 + kh * 3 + kw] =
                            xv[kd] * (1.f - f) + xv[kd + 1] * f;
                }
            const float* wp = w + ci * 27;   // block-uniform -> s_load path
#pragma unroll
            for (int co = 0; co < 64; ++co) {
                float s = acc[co];
#pragma unroll
                for (int t = 0; t < 27; ++t)
                    s = fmaf(Gv[t], wp[co * 1728 + t], s);
                acc[co] = s;
            }
        }
    }
    if (tx < 56) {
        const size_t sp = (size_t)dd * HW + (size_t)(h_base + ty) * 56 + tx;
#pragma unroll
        for (int co = 0; co < 64; ++co)
            dst[(size_t)(n * 64 + co) * (DD_ * HW) + sp] = acc[co];
    }
}

// ---------------- per-channel sum / sumsq reduction ----------------------------
__global__ __launch_bounds__(256) void k_stats(
    const float* __restrict__ src, float* __restrict__ sums, float* __restrict__ sqs)
{
    const int c = blockIdx.x, n = blockIdx.y;
    const float* p = src + ((size_t)n * 64 + c) * DHW;
    float s = 0.f, q = 0.f;
    for (int i = threadIdx.x; i < DHW; i += 256) {
        float v = p[i];
        s += v;
        q = fmaf(v, v, q);
    }
    for (int o = 32; o > 0; o >>= 1) {
        s += __shfl_down(s, o);
        q += __shfl_down(q, o);
    }
    __shared__ float ls[4], lq[4];
    const int wv = threadIdx.x >> 6, lane = threadIdx.x & 63;
    if (lane == 0) { ls[wv] = s; lq[wv] = q; }
    __syncthreads();
    if (threadIdx.x == 0) {
        s = ls[0] + ls[1] + ls[2] + ls[3];
        q = lq[0] + lq[1] + lq[2] + lq[3];
        atomicAdd(&sums[c], s);
        atomicAdd(&sqs[c], q);
    }
}

// ---------------- finalize BN: scale/shift -------------------------------------
__global__ void k_finalize(const float* __restrict__ sums, const float* __restrict__ sqs,
                           const float* __restrict__ gamma, const float* __restrict__ beta,
                           float* __restrict__ scale, float* __restrict__ shift)
{
    const int c = threadIdx.x; // 64 threads
    const float mean = sums[c] / CNT;
    const float var = sqs[c] / CNT - mean * mean;
    const float sc = gamma[c] * rsqrtf(var + 1e-5f);
    scale[c] = sc;
    shift[c] = fmaf(-mean, sc, beta[c]);
}

// ---------------- apply BN + ReLU in place (float4) ----------------------------
__global__ __launch_bounds__(256) void k_bnrelu(
    float4* __restrict__ buf, const float* __restrict__ scale, const float* __restrict__ shift)
{
    const int i = blockIdx.x * 256 + threadIdx.x;   // < 6422528
    const int c = (i / 12544) & 63;                  // wave-uniform
    const float sc = scale[c], sh = shift[c];
    float4 v = buf[i];
    v.x = fmaxf(fmaf(v.x, sc, sh), 0.f);
    v.y = fmaxf(fmaf(v.y, sc, sh), 0.f);
    v.z = fmaxf(fmaf(v.z, sc, sh), 0.f);
    v.w = fmaxf(fmaf(v.w, sc, sh), 0.f);
    buf[i] = v;
}

// ---------------- BN + residual + ReLU in place (float4) -----------------------
__global__ __launch_bounds__(256) void k_residual(
    float4* __restrict__ out, const float4* __restrict__ x,
    const float* __restrict__ scale, const float* __restrict__ shift)
{
    const int i = blockIdx.x * 256 + threadIdx.x;   // < 6422528
    const int c = (i / 12544) & 63;
    const float sc = scale[c], sh = shift[c];
    float4 v = out[i];
    const float4 xv = x[i];
    v.x = fmaxf(fmaf(v.x, sc, sh) + xv.x, 0.f);
    v.y = fmaxf(fmaf(v.y, sc, sh) + xv.y, 0.f);
    v.z = fmaxf(fmaf(v.z, sc, sh) + xv.z, 0.f);
    v.w = fmaxf(fmaf(v.w, sc, sh) + xv.w, 0.f);
    out[i] = v;
}

extern "C" void kernel_launch(void* const* d_in, const int* in_sizes, int n_in,
                              void* d_out, int out_size, void* d_ws, size_t ws_size,
                              hipStream_t stream) {
    const float* x     = (const float*)d_in[0];
    const float* w_off = (const float*)d_in[1];
    const float* b_off = (const float*)d_in[2];
    const float* w1    = (const float*)d_in[3];
    const float* w2    = (const float*)d_in[4];
    const float* b2    = (const float*)d_in[5];
    const float* g1    = (const float*)d_in[6];
    const float* be1   = (const float*)d_in[7];
    const float* g2    = (const float*)d_in[8];
    const float* be2   = (const float*)d_in[9];

    float* out  = (float*)d_out;
    float* off  = out + NEL;                 // second tuple element
    float* buf1 = (float*)d_ws;              // deform-conv output, 25690112 floats
    float* st   = buf1 + NEL;                // 512 floats of stats
    // st layout: 0 sum1 | 64 sq1 | 128 scale1 | 192 shift1 | 256 sum2 | 320 sq2 | 384 scale2 | 448 shift2

    hipMemsetAsync(st, 0, 512 * sizeof(float), stream);

    const dim3 cgrid(14, 128);   // 14 h-tiles x (n*d)
    k_conv3<8><<<cgrid, 256, 0, stream>>>(x, w_off, b_off, off);
    k_deform<<<cgrid, 256, 0, stream>>>(x, off, w1, buf1);
    k_stats<<<dim3(64, 8), 256, 0, stream>>>(buf1, st + 0, st + 64);
    k_finalize<<<1, 64, 0, stream>>>(st + 0, st + 64, g1, be1, st + 128, st + 192);
    k_bnrelu<<<25088, 256, 0, stream>>>((float4*)buf1, st + 128, st + 192);
    k_conv3<64><<<cgrid, 256, 0, stream>>>(buf1, w2, b2, out);
    k_stats<<<dim3(64, 8), 256, 0, stream>>>(out, st + 256, st + 320);
    k_finalize<<<1, 64, 0, stream>>>(st + 256, st + 320, g2, be2, st + 384, st + 448);
    k_residual<<<25088, 256, 0, stream>>>((float4*)out, (const float4*)x, st + 384, st + 448);
}